// Round 1
// baseline (1210.723 us; speedup 1.0000x reference)
//
#include <hip/hip_runtime.h>
#include <hip/hip_bf16.h>
#include <math.h>

// Problem dims (fixed by the reference)
#define B_  64
#define S_  512
#define D_  1024
#define E2_ 1024
#define WROW (D_ + E2_)   // 2048, row stride of w_weight

// ---------------------------------------------------------------------------
// Kernel A: t[b][k] = sum_d dec[b,d] * W[k,d] + bias[k]   (Wd = w[:, :D])
// One block per k (1024 blocks, 256 threads). Stage W row in LDS.
// ---------------------------------------------------------------------------
__global__ __launch_bounds__(256) void dec_proj_kernel(
        const float* __restrict__ dec,    // (B, D)
        const float* __restrict__ w,      // (D, 2048)
        const float* __restrict__ bias,   // (D)
        float* __restrict__ t)            // (B, D)
{
    __shared__ float wrow[D_];
    __shared__ float red[256];
    const int k = blockIdx.x;
    const int tid = threadIdx.x;

    const float* wr = w + (size_t)k * WROW;   // first D_ cols = Wd[k]
    for (int i = tid; i < D_; i += 256) wrow[i] = wr[i];
    __syncthreads();

    const int b = tid >> 2;   // 0..63
    const int q = tid & 3;    // 0..3, quarter of d-range
    const float* dp = dec + b * D_ + q * 256;
    const float* wp = wrow + q * 256;
    float acc = 0.f;
    #pragma unroll 8
    for (int i = 0; i < 256; ++i) acc = fmaf(dp[i], wp[i], acc);
    red[tid] = acc;
    __syncthreads();
    if (q == 0) {
        float s = red[tid] + red[tid + 1] + red[tid + 2] + red[tid + 3];
        t[b * D_ + k] = s + bias[k];
    }
}

// ---------------------------------------------------------------------------
// Kernel B: fused energy + v-dot.
//   att[m] = sum_n tanh( sum_k enc[m,k]*We[n,k] + t[b(m),n] ) * v[n]
// m = b*S + s (32768 rows). Block = 64-row m-tile, loops all n and k.
// 256 threads, 4x4 micro-tile per thread, f32, LDS-staged tiles.
// ---------------------------------------------------------------------------
#define BM 64
#define BN 64
#define BK 16

__global__ __launch_bounds__(256) void energy_kernel(
        const float* __restrict__ enc,    // (B*S, E2) row-major
        const float* __restrict__ w,      // (D, 2048); We at col offset D_
        const float* __restrict__ t,      // (B, D)  (dec_proj + bias)
        const float* __restrict__ v,      // (D)
        float* __restrict__ att)          // (B*S)
{
    __shared__ __align__(16) float As[BK][BM];
    __shared__ __align__(16) float Bs[BK][BN];
    __shared__ __align__(16) float red[BM][16];

    const int m0 = blockIdx.x * BM;
    const int b  = m0 >> 9;              // / S_ (tile never spans batches)
    const int tid = threadIdx.x;
    const int ty = tid >> 4, tx = tid & 15;
    const int lr = tid >> 2;             // staging: row within tile (0..63)
    const int lq = tid & 3;              // staging: k-quarter (float4)

    float att_acc[4] = {0.f, 0.f, 0.f, 0.f};

    for (int nt = 0; nt < D_ / BN; ++nt) {
        const int n0 = nt * BN;
        float acc[4][4] = {};

        for (int kt = 0; kt < E2_ / BK; ++kt) {
            const int k0 = kt * BK;
            // stage A tile (enc): row m0+lr, cols k0 + lq*4 .. +4
            float4 a4 = *reinterpret_cast<const float4*>(
                enc + (size_t)(m0 + lr) * E2_ + k0 + lq * 4);
            As[lq * 4 + 0][lr] = a4.x;
            As[lq * 4 + 1][lr] = a4.y;
            As[lq * 4 + 2][lr] = a4.z;
            As[lq * 4 + 3][lr] = a4.w;
            // stage B tile (We): row n0+lr, cols D_ + k0 + lq*4
            float4 b4 = *reinterpret_cast<const float4*>(
                w + (size_t)(n0 + lr) * WROW + D_ + k0 + lq * 4);
            Bs[lq * 4 + 0][lr] = b4.x;
            Bs[lq * 4 + 1][lr] = b4.y;
            Bs[lq * 4 + 2][lr] = b4.z;
            Bs[lq * 4 + 3][lr] = b4.w;
            __syncthreads();

            #pragma unroll
            for (int kk = 0; kk < BK; ++kk) {
                float4 av = *reinterpret_cast<const float4*>(&As[kk][ty * 4]);
                float4 bv = *reinterpret_cast<const float4*>(&Bs[kk][tx * 4]);
                float a[4] = {av.x, av.y, av.z, av.w};
                float bb[4] = {bv.x, bv.y, bv.z, bv.w};
                #pragma unroll
                for (int i = 0; i < 4; ++i)
                    #pragma unroll
                    for (int j = 0; j < 4; ++j)
                        acc[i][j] = fmaf(a[i], bb[j], acc[i][j]);
            }
            __syncthreads();
        }

        // epilogue for this n-tile: tanh + v-weighted reduce over n
        #pragma unroll
        for (int j = 0; j < 4; ++j) {
            const int n = n0 + tx * 4 + j;
            const float tv = t[b * D_ + n];
            const float vv = v[n];
            #pragma unroll
            for (int i = 0; i < 4; ++i) {
                float e = tanhf(acc[i][j] + tv);
                att_acc[i] = fmaf(e, vv, att_acc[i]);
            }
        }
    }

    // reduce partial attention across the 16 tx columns
    #pragma unroll
    for (int i = 0; i < 4; ++i) red[ty * 4 + i][tx] = att_acc[i];
    __syncthreads();
    if (tid < 64) {
        float s = 0.f;
        #pragma unroll
        for (int x = 0; x < 16; ++x) s += red[tid][x];
        att[m0 + tid] = s;
    }
}

// ---------------------------------------------------------------------------
// Kernel C: masked softmax over s per batch. One block per b.
// ---------------------------------------------------------------------------
__global__ __launch_bounds__(256) void softmax_kernel(
        const float* __restrict__ att,    // (B, S)
        const int* __restrict__ mask,     // (B, S)
        float* __restrict__ wout)         // (B, S)
{
    __shared__ float red[256];
    const int b = blockIdx.x;
    const int tid = threadIdx.x;

    float x0 = att[b * S_ + tid];
    float x1 = att[b * S_ + 256 + tid];
    bool m0v = (mask[b * S_ + tid] != 0);
    bool m1v = (mask[b * S_ + 256 + tid] != 0);
    if (!m0v) x0 = -INFINITY;
    if (!m1v) x1 = -INFINITY;

    float m = fmaxf(x0, x1);
    red[tid] = m;
    __syncthreads();
    for (int o = 128; o > 0; o >>= 1) {
        if (tid < o) red[tid] = fmaxf(red[tid], red[tid + o]);
        __syncthreads();
    }
    m = red[0];
    __syncthreads();

    float e0 = m0v ? expf(x0 - m) : 0.f;
    float e1 = m1v ? expf(x1 - m) : 0.f;
    red[tid] = e0 + e1;
    __syncthreads();
    for (int o = 128; o > 0; o >>= 1) {
        if (tid < o) red[tid] += red[tid + o];
        __syncthreads();
    }
    const float inv = 1.f / red[0];
    wout[b * S_ + tid] = e0 * inv;
    wout[b * S_ + 256 + tid] = e1 * inv;
}

// ---------------------------------------------------------------------------
// Kernel D: out[b][e] = sum_s wgt[b,s] * enc[b,s,e]
// grid (E2/256, B), coalesced over e; weights staged in LDS.
// ---------------------------------------------------------------------------
__global__ __launch_bounds__(256) void attout_kernel(
        const float* __restrict__ wgt,    // (B, S)
        const float* __restrict__ enc,    // (B, S, E2)
        float* __restrict__ out)          // (B, E2)
{
    __shared__ float wsm[S_];
    const int b = blockIdx.y;
    const int e = blockIdx.x * 256 + threadIdx.x;
    for (int i = threadIdx.x; i < S_; i += 256) wsm[i] = wgt[b * S_ + i];
    __syncthreads();

    const float* ep = enc + (size_t)b * S_ * E2_ + e;
    float acc = 0.f;
    #pragma unroll 8
    for (int s = 0; s < S_; ++s)
        acc = fmaf(wsm[s], ep[(size_t)s * E2_], acc);
    out[b * E2_ + e] = acc;
}

// ---------------------------------------------------------------------------
extern "C" void kernel_launch(void* const* d_in, const int* in_sizes, int n_in,
                              void* d_out, int out_size, void* d_ws, size_t ws_size,
                              hipStream_t stream) {
    const float* dec  = (const float*)d_in[0];   // (B, D)
    const float* enc  = (const float*)d_in[1];   // (B, S, E2)
    const int*   mask = (const int*)d_in[2];     // (B, S)
    const float* w    = (const float*)d_in[3];   // (D, D+E2)
    const float* bias = (const float*)d_in[4];   // (D)
    const float* v    = (const float*)d_in[5];   // (D)
    float* out = (float*)d_out;                  // (B, 1, E2) -> B*E2

    float* t_buf   = (float*)d_ws;               // B*D      = 65536 f32
    float* att_buf = t_buf + B_ * D_;            // B*S      = 32768 f32
    float* wgt_buf = att_buf + B_ * S_;          // B*S      = 32768 f32

    dec_proj_kernel<<<D_, 256, 0, stream>>>(dec, w, bias, t_buf);
    energy_kernel<<<(B_ * S_) / BM, 256, 0, stream>>>(enc, w, t_buf, v, att_buf);
    softmax_kernel<<<B_, 256, 0, stream>>>(att_buf, mask, wgt_buf);
    attout_kernel<<<dim3(E2_ / 256, B_), 256, 0, stream>>>(wgt_buf, enc, out);
}

// Round 2
// 211.264 us; speedup vs baseline: 5.7308x; 5.7308x over previous
//
#include <hip/hip_runtime.h>
#include <hip/hip_bf16.h>
#include <math.h>

// Problem dims (fixed by the reference)
#define B_  64
#define S_  512
#define D_  1024
#define E2_ 1024
#define WROW (D_ + E2_)   // 2048, row stride of w_weight
#define NTILES 8          // D_ / BNE

typedef __attribute__((ext_vector_type(8))) short bf16x8;
typedef __attribute__((ext_vector_type(4))) float f32x4;
typedef __attribute__((ext_vector_type(8))) unsigned short u16x8;

// round-to-nearest-even f32 -> bf16
__device__ __forceinline__ unsigned short f2bf(float f) {
    unsigned u = __float_as_uint(f);
    u = (u + 0x7FFFu + ((u >> 16) & 1u)) >> 16;
    return (unsigned short)u;
}

__device__ __forceinline__ void load_lds16(const void* g, void* l) {
    __builtin_amdgcn_global_load_lds(
        (__attribute__((address_space(1))) void*)(void*)g,
        (__attribute__((address_space(3))) void*)l,
        16, 0, 0);
}

// ---------------------------------------------------------------------------
// Convert enc (B*S*E2 f32) -> bf16, 8 elems / thread-iter
// ---------------------------------------------------------------------------
__global__ __launch_bounds__(256) void conv_enc_kernel(
        const float* __restrict__ in, unsigned short* __restrict__ out, int n8)
{
    int i = blockIdx.x * 256 + threadIdx.x;
    const int stride = gridDim.x * 256;
    for (; i < n8; i += stride) {
        float4 a = *reinterpret_cast<const float4*>(in + (size_t)i * 8);
        float4 b = *reinterpret_cast<const float4*>(in + (size_t)i * 8 + 4);
        u16x8 o;
        o[0] = f2bf(a.x); o[1] = f2bf(a.y); o[2] = f2bf(a.z); o[3] = f2bf(a.w);
        o[4] = f2bf(b.x); o[5] = f2bf(b.y); o[6] = f2bf(b.z); o[7] = f2bf(b.w);
        *reinterpret_cast<u16x8*>(out + (size_t)i * 8) = o;
    }
}

// ---------------------------------------------------------------------------
// Convert We = w[:, D_:] (strided in w) -> dense bf16 (D_ x E2_)
// one block per k-row
// ---------------------------------------------------------------------------
__global__ __launch_bounds__(256) void conv_we_kernel(
        const float* __restrict__ w, unsigned short* __restrict__ web)
{
    const int k = blockIdx.x;
    const int j = threadIdx.x * 4;
    float4 a = *reinterpret_cast<const float4*>(w + (size_t)k * WROW + D_ + j);
    ushort4 o;
    o.x = f2bf(a.x); o.y = f2bf(a.y); o.z = f2bf(a.z); o.w = f2bf(a.w);
    *reinterpret_cast<ushort4*>(web + (size_t)k * E2_ + j) = o;
}

// ---------------------------------------------------------------------------
// Kernel A: t[b][k] = sum_d dec[b,d] * W[k,d] + bias[k]   (Wd = w[:, :D]), f32
// ---------------------------------------------------------------------------
__global__ __launch_bounds__(256) void dec_proj_kernel(
        const float* __restrict__ dec,    // (B, D)
        const float* __restrict__ w,      // (D, 2048)
        const float* __restrict__ bias,   // (D)
        float* __restrict__ t)            // (B, D)
{
    __shared__ float wrow[D_];
    __shared__ float red[256];
    const int k = blockIdx.x;
    const int tid = threadIdx.x;

    const float* wr = w + (size_t)k * WROW;
    for (int i = tid; i < D_; i += 256) wrow[i] = wr[i];
    __syncthreads();

    const int b = tid >> 2;
    const int q = tid & 3;
    const float* dp = dec + b * D_ + q * 256;
    const float* wp = wrow + q * 256;
    float acc = 0.f;
    #pragma unroll 8
    for (int i = 0; i < 256; ++i) acc = fmaf(dp[i], wp[i], acc);
    red[tid] = acc;
    __syncthreads();
    if (q == 0) {
        float s = red[tid] + red[tid + 1] + red[tid + 2] + red[tid + 3];
        t[b * D_ + k] = s + bias[k];
    }
}

// ---------------------------------------------------------------------------
// Kernel B: bf16 MFMA fused energy + tanh + v-dot.
//   att_part[m][nt] = sum_{n in tile nt} tanh(enc[m,:]·We[n,:] + t[b,n]) * v[n]
// Tile: BM=128, BN=128, BK=64. 256 threads = 4 waves (2x2), each wave 64x64.
// LDS tiles st-swizzled: logical (row r, byte kb) at phys r*128 + (kb^((r&7)<<4)).
// Staged via global_load_lds (linear dest) with inverse-swizzled global source.
// ---------------------------------------------------------------------------
#define BME 128
#define BNE 128
#define BKE 64

__global__ __launch_bounds__(256) void energy_mfma_kernel(
        const unsigned short* __restrict__ encb,  // (B*S, E2) bf16
        const unsigned short* __restrict__ web,   // (D, E2) bf16
        const float* __restrict__ t,              // (B, D)
        const float* __restrict__ v,              // (D)
        float* __restrict__ att_part)             // (B*S, NTILES)
{
    __shared__ __align__(16) unsigned short As[BME * BKE];
    __shared__ __align__(16) unsigned short Bs[BNE * BKE];
    __shared__ float tv_s[BNE];
    __shared__ float vv_s[BNE];
    __shared__ float red[2][BME];

    const int m0 = blockIdx.x * BME;
    const int nt = blockIdx.y;
    const int n0 = nt * BNE;
    const int b  = m0 >> 9;                 // tile never spans batches (128<512)
    const int tid = threadIdx.x;
    const int wid = tid >> 6;
    const int l   = tid & 63;
    const int wm  = wid >> 1;               // wave row (0..1)
    const int wn  = wid & 1;                // wave col (0..1)

    if (tid < BNE) { tv_s[tid] = t[b * D_ + n0 + tid]; vv_s[tid] = v[n0 + tid]; }

    // --- staging source address (inverse-swizzled global) ---
    // chunk c = wid*4 + j (1024B each); lane l -> row c*8 + (l>>3),
    // swizzled col (bf16): 8*((l&7) ^ (l>>3))
    const int lr8 = l >> 3;
    const int lk  = 8 * ((l & 7) ^ lr8);
    const unsigned short* gA = encb + (size_t)m0 * E2_;
    const unsigned short* gB = web  + (size_t)n0 * E2_;

    // --- frag read offsets (bytes, swizzled) ---
    // A frag (mi,kk): r = wm*64+mi*16+(l&15), kb = kk*64+(l>>4)*16
    // phys = r*128 + (kb ^ ((l&7)<<4))
    const int rA = wm * 64 + (l & 15);
    const int rB = wn * 64 + (l & 15);
    const int kswz = (l & 7) << 4;
    const int khi  = (l >> 4) << 4;

    f32x4 acc[4][4] = {};

    for (int kt = 0; kt < E2_ / BKE; ++kt) {
        const int k0 = kt * BKE;
        #pragma unroll
        for (int j = 0; j < 4; ++j) {
            const int c = wid * 4 + j;
            const int row = c * 8 + lr8;
            load_lds16(gA + (size_t)row * E2_ + k0 + lk, (char*)As + c * 1024);
            load_lds16(gB + (size_t)row * E2_ + k0 + lk, (char*)Bs + c * 1024);
        }
        __syncthreads();   // compiler drains vmcnt+lgkmcnt here

        #pragma unroll
        for (int kk = 0; kk < 2; ++kk) {
            const int kb = (kk * 64 + khi) ^ kswz;
            bf16x8 a[4], bb[4];
            #pragma unroll
            for (int mi = 0; mi < 4; ++mi)
                a[mi] = *reinterpret_cast<const bf16x8*>(
                    (const char*)As + (rA + mi * 16) * 128 + kb);
            #pragma unroll
            for (int ni = 0; ni < 4; ++ni)
                bb[ni] = *reinterpret_cast<const bf16x8*>(
                    (const char*)Bs + (rB + ni * 16) * 128 + kb);
            #pragma unroll
            for (int mi = 0; mi < 4; ++mi)
                #pragma unroll
                for (int ni = 0; ni < 4; ++ni)
                    acc[mi][ni] = __builtin_amdgcn_mfma_f32_16x16x32_bf16(
                        a[mi], bb[ni], acc[mi][ni], 0, 0, 0);
        }
        __syncthreads();
    }

    // --- epilogue: tanh + v-dot, reduce over n within block ---
    // D frag mapping: col = l&15, row = (l>>4)*4 + j  [m89-verified]
    #pragma unroll
    for (int mi = 0; mi < 4; ++mi) {
        float P[4] = {0.f, 0.f, 0.f, 0.f};
        #pragma unroll
        for (int ni = 0; ni < 4; ++ni) {
            const int nl = wn * 64 + ni * 16 + (l & 15);
            const float tvv = tv_s[nl];
            const float vvv = vv_s[nl];
            #pragma unroll
            for (int j = 0; j < 4; ++j) {
                float e = tanhf(acc[mi][ni][j] + tvv);
                P[j] = fmaf(e, vvv, P[j]);
            }
        }
        #pragma unroll
        for (int j = 0; j < 4; ++j) {
            float p = P[j];
            p += __shfl_xor(p, 1);
            p += __shfl_xor(p, 2);
            p += __shfl_xor(p, 4);
            p += __shfl_xor(p, 8);
            if ((l & 15) == 0)
                red[wn][wm * 64 + mi * 16 + (l >> 4) * 4 + j] = p;
        }
    }
    __syncthreads();
    if (tid < BME)
        att_part[(size_t)(m0 + tid) * NTILES + nt] = red[0][tid] + red[1][tid];
}

// ---------------------------------------------------------------------------
// Kernel C: reduce partials + masked softmax over s per batch. One block per b.
// ---------------------------------------------------------------------------
__global__ __launch_bounds__(256) void softmax_kernel(
        const float* __restrict__ att_part,  // (B*S, NTILES)
        const int* __restrict__ mask,        // (B, S)
        float* __restrict__ wout)            // (B, S)
{
    __shared__ float red[256];
    const int b = blockIdx.x;
    const int tid = threadIdx.x;

    float x0 = 0.f, x1 = 0.f;
    #pragma unroll
    for (int p = 0; p < NTILES; ++p) {
        x0 += att_part[(size_t)(b * S_ + tid) * NTILES + p];
        x1 += att_part[(size_t)(b * S_ + 256 + tid) * NTILES + p];
    }
    bool m0v = (mask[b * S_ + tid] != 0);
    bool m1v = (mask[b * S_ + 256 + tid] != 0);
    if (!m0v) x0 = -INFINITY;
    if (!m1v) x1 = -INFINITY;

    float m = fmaxf(x0, x1);
    red[tid] = m;
    __syncthreads();
    for (int o = 128; o > 0; o >>= 1) {
        if (tid < o) red[tid] = fmaxf(red[tid], red[tid + o]);
        __syncthreads();
    }
    m = red[0];
    __syncthreads();

    float e0 = m0v ? expf(x0 - m) : 0.f;
    float e1 = m1v ? expf(x1 - m) : 0.f;
    red[tid] = e0 + e1;
    __syncthreads();
    for (int o = 128; o > 0; o >>= 1) {
        if (tid < o) red[tid] += red[tid + o];
        __syncthreads();
    }
    const float inv = 1.f / red[0];
    wout[b * S_ + tid] = e0 * inv;
    wout[b * S_ + 256 + tid] = e1 * inv;
}

// ---------------------------------------------------------------------------
// Kernel D: out[b][e] = sum_s wgt[b,s] * enc[b,s,e]  (f32, coalesced over e)
// ---------------------------------------------------------------------------
__global__ __launch_bounds__(256) void attout_kernel(
        const float* __restrict__ wgt,    // (B, S)
        const float* __restrict__ enc,    // (B, S, E2)
        float* __restrict__ out)          // (B, E2)
{
    __shared__ float wsm[S_];
    const int b = blockIdx.y;
    const int e = blockIdx.x * 256 + threadIdx.x;
    for (int i = threadIdx.x; i < S_; i += 256) wsm[i] = wgt[b * S_ + i];
    __syncthreads();

    const float* ep = enc + (size_t)b * S_ * E2_ + e;
    float acc = 0.f;
    #pragma unroll 8
    for (int s = 0; s < S_; ++s)
        acc = fmaf(wsm[s], ep[(size_t)s * E2_], acc);
    out[b * E2_ + e] = acc;
}

// ---------------------------------------------------------------------------
extern "C" void kernel_launch(void* const* d_in, const int* in_sizes, int n_in,
                              void* d_out, int out_size, void* d_ws, size_t ws_size,
                              hipStream_t stream) {
    const float* dec  = (const float*)d_in[0];   // (B, D)
    const float* enc  = (const float*)d_in[1];   // (B, S, E2)
    const int*   mask = (const int*)d_in[2];     // (B, S)
    const float* w    = (const float*)d_in[3];   // (D, D+E2)
    const float* bias = (const float*)d_in[4];   // (D)
    const float* v    = (const float*)d_in[5];   // (D)
    float* out = (float*)d_out;                  // (B, 1, E2)

    // workspace layout
    float* t_buf    = (float*)d_ws;                      // B*D         f32
    float* att_part = t_buf + B_ * D_;                   // B*S*NTILES  f32
    float* wgt_buf  = att_part + B_ * S_ * NTILES;       // B*S         f32
    unsigned short* encb = (unsigned short*)(wgt_buf + B_ * S_);  // B*S*E2 bf16
    unsigned short* web  = encb + (size_t)B_ * S_ * E2_;          // D*E2   bf16

    const int enc_n8 = (B_ * S_ * E2_) / 8;
    conv_enc_kernel<<<4096, 256, 0, stream>>>(enc, encb, enc_n8);
    conv_we_kernel<<<D_, 256, 0, stream>>>(w, web);
    dec_proj_kernel<<<D_, 256, 0, stream>>>(dec, w, bias, t_buf);
    energy_mfma_kernel<<<dim3((B_ * S_) / BME, NTILES), 256, 0, stream>>>(
        encb, web, t_buf, v, att_part);
    softmax_kernel<<<B_, 256, 0, stream>>>(att_part, mask, wgt_buf);
    attout_kernel<<<dim3(E2_ / 256, B_), 256, 0, stream>>>(wgt_buf, enc, out);
}

// Round 3
// 193.916 us; speedup vs baseline: 6.2435x; 1.0895x over previous
//
#include <hip/hip_runtime.h>
#include <hip/hip_bf16.h>
#include <math.h>

// Problem dims (fixed by the reference)
#define B_  64
#define S_  512
#define D_  1024
#define E2_ 1024
#define WROW (D_ + E2_)   // 2048, row stride of w_weight
#define NTILES 8          // D_ / BNE

typedef __attribute__((ext_vector_type(8))) short bf16x8;
typedef __attribute__((ext_vector_type(4))) float f32x4;
typedef __attribute__((ext_vector_type(8))) unsigned short u16x8;

// round-to-nearest-even f32 -> bf16
__device__ __forceinline__ unsigned short f2bf(float f) {
    unsigned u = __float_as_uint(f);
    u = (u + 0x7FFFu + ((u >> 16) & 1u)) >> 16;
    return (unsigned short)u;
}

__device__ __forceinline__ void load_lds16(const void* g, void* l) {
    __builtin_amdgcn_global_load_lds(
        (__attribute__((address_space(1))) void*)(void*)g,
        (__attribute__((address_space(3))) void*)l,
        16, 0, 0);
}

// branch-free tanh via v_exp_f32: tanh(x) = sign(x)*(e^{2|x|}-1)/(e^{2|x|}+1)
__device__ __forceinline__ float fast_tanh(float x) {
    float ax = fminf(fabsf(x), 16.0f);                       // tanh(16)==1.0f
    float t  = __builtin_amdgcn_exp2f(ax * 2.8853900817779268f); // e^{2ax}
    float r  = (t - 1.0f) * __builtin_amdgcn_rcpf(t + 1.0f);
    return copysignf(r, x);
}

// ---------------------------------------------------------------------------
// Convert enc (B*S*E2 f32) -> bf16, 8 elems / thread-iter
// ---------------------------------------------------------------------------
__global__ __launch_bounds__(256) void conv_enc_kernel(
        const float* __restrict__ in, unsigned short* __restrict__ out, int n8)
{
    int i = blockIdx.x * 256 + threadIdx.x;
    const int stride = gridDim.x * 256;
    for (; i < n8; i += stride) {
        float4 a = *reinterpret_cast<const float4*>(in + (size_t)i * 8);
        float4 b = *reinterpret_cast<const float4*>(in + (size_t)i * 8 + 4);
        u16x8 o;
        o[0] = f2bf(a.x); o[1] = f2bf(a.y); o[2] = f2bf(a.z); o[3] = f2bf(a.w);
        o[4] = f2bf(b.x); o[5] = f2bf(b.y); o[6] = f2bf(b.z); o[7] = f2bf(b.w);
        *reinterpret_cast<u16x8*>(out + (size_t)i * 8) = o;
    }
}

// ---------------------------------------------------------------------------
// Convert We = w[:, D_:] (strided in w) -> dense bf16 (D_ x E2_)
// ---------------------------------------------------------------------------
__global__ __launch_bounds__(256) void conv_we_kernel(
        const float* __restrict__ w, unsigned short* __restrict__ web)
{
    const int k = blockIdx.x;
    const int j = threadIdx.x * 4;
    float4 a = *reinterpret_cast<const float4*>(w + (size_t)k * WROW + D_ + j);
    ushort4 o;
    o.x = f2bf(a.x); o.y = f2bf(a.y); o.z = f2bf(a.z); o.w = f2bf(a.w);
    *reinterpret_cast<ushort4*>(web + (size_t)k * E2_ + j) = o;
}

// ---------------------------------------------------------------------------
// Kernel A: t[b][k] = sum_d dec[b,d] * W[k,d] + bias[k]   (Wd = w[:, :D]), f32
// ---------------------------------------------------------------------------
__global__ __launch_bounds__(256) void dec_proj_kernel(
        const float* __restrict__ dec,    // (B, D)
        const float* __restrict__ w,      // (D, 2048)
        const float* __restrict__ bias,   // (D)
        float* __restrict__ t)            // (B, D)
{
    __shared__ float wrow[D_];
    __shared__ float red[256];
    const int k = blockIdx.x;
    const int tid = threadIdx.x;

    const float* wr = w + (size_t)k * WROW;
    for (int i = tid; i < D_; i += 256) wrow[i] = wr[i];
    __syncthreads();

    const int b = tid >> 2;
    const int q = tid & 3;
    const float* dp = dec + b * D_ + q * 256;
    const float* wp = wrow + q * 256;
    float acc = 0.f;
    #pragma unroll 8
    for (int i = 0; i < 256; ++i) acc = fmaf(dp[i], wp[i], acc);
    red[tid] = acc;
    __syncthreads();
    if (q == 0) {
        float s = red[tid] + red[tid + 1] + red[tid + 2] + red[tid + 3];
        t[b * D_ + k] = s + bias[k];
    }
}

// ---------------------------------------------------------------------------
// Kernel B: bf16 MFMA fused energy + tanh + v-dot.
// Tile: BM=128, BN=128, BK=64; each block processes TWO n-tiles (A-reuse).
// Grid: (256 m-tiles, 4 n-pairs), XCD-bijective swizzled (1024 % 8 == 0).
// LDS st-swizzled: logical (row r, byte kb) at phys r*128 + (kb^((r&7)<<4)),
// staged via global_load_lds (linear dest) with inverse-swizzled global src.
// ---------------------------------------------------------------------------
#define BME 128
#define BNE 128
#define BKE 64

__global__ __launch_bounds__(256) void energy_mfma_kernel(
        const unsigned short* __restrict__ encb,  // (B*S, E2) bf16
        const unsigned short* __restrict__ web,   // (D, E2) bf16
        const float* __restrict__ t,              // (B, D)
        const float* __restrict__ v,              // (D)
        float* __restrict__ att_part)             // (B*S, NTILES)
{
    __shared__ __align__(16) unsigned short As[BME * BKE];
    __shared__ __align__(16) unsigned short Bs[BNE * BKE];
    __shared__ float tv_s[2][BNE];
    __shared__ float vv_s[2][BNE];
    __shared__ float red[2][BME];

    // XCD-bijective block swizzle: each XCD gets one n-pair, contiguous m
    const int lin   = blockIdx.y * gridDim.x + blockIdx.x;  // 0..1023
    const int swz   = (lin & 7) * 128 + (lin >> 3);
    const int mblk  = swz & 255;
    const int ypair = swz >> 8;             // 0..3

    const int m0 = mblk * BME;
    const int b  = m0 >> 9;                 // tile never spans batches
    const int tid = threadIdx.x;
    const int wid = tid >> 6;
    const int l   = tid & 63;
    const int wm  = wid >> 1;               // wave row (0..1)
    const int wn  = wid & 1;                // wave col (0..1)

    {   // preload t and v for both n-tiles of this pair
        const int half = tid >> 7, idx = tid & 127;
        const int n = (ypair * 2 + half) * BNE + idx;
        tv_s[half][idx] = t[b * D_ + n];
        vv_s[half][idx] = v[n];
    }

    // --- staging source address (inverse-swizzled global) ---
    const int lr8 = l >> 3;
    const int lk  = 8 * ((l & 7) ^ lr8);
    const unsigned short* gA = encb + (size_t)m0 * E2_;

    // --- frag read offsets (bytes, swizzled) ---
    const int rA = wm * 64 + (l & 15);
    const int rB = wn * 64 + (l & 15);
    const int kswz = (l & 7) << 4;
    const int khi  = (l >> 4) << 4;

    for (int nt2 = 0; nt2 < 2; ++nt2) {
        const int n0 = (ypair * 2 + nt2) * BNE;
        const unsigned short* gB = web + (size_t)n0 * E2_;

        f32x4 acc[4][4] = {};

        for (int kt = 0; kt < E2_ / BKE; ++kt) {
            const int k0 = kt * BKE;
            #pragma unroll
            for (int j = 0; j < 4; ++j) {
                const int c = wid * 4 + j;
                const int row = c * 8 + lr8;
                load_lds16(gA + (size_t)row * E2_ + k0 + lk, (char*)As + c * 1024);
                load_lds16(gB + (size_t)row * E2_ + k0 + lk, (char*)Bs + c * 1024);
            }
            __syncthreads();   // compiler drains vmcnt+lgkmcnt here

            #pragma unroll
            for (int kk = 0; kk < 2; ++kk) {
                const int kb = (kk * 64 + khi) ^ kswz;
                bf16x8 a[4], bb[4];
                #pragma unroll
                for (int mi = 0; mi < 4; ++mi)
                    a[mi] = *reinterpret_cast<const bf16x8*>(
                        (const char*)As + (rA + mi * 16) * 128 + kb);
                #pragma unroll
                for (int ni = 0; ni < 4; ++ni)
                    bb[ni] = *reinterpret_cast<const bf16x8*>(
                        (const char*)Bs + (rB + ni * 16) * 128 + kb);
                #pragma unroll
                for (int mi = 0; mi < 4; ++mi)
                    #pragma unroll
                    for (int ni = 0; ni < 4; ++ni)
                        acc[mi][ni] = __builtin_amdgcn_mfma_f32_16x16x32_bf16(
                            a[mi], bb[ni], acc[mi][ni], 0, 0, 0);
            }
            __syncthreads();
        }

        // --- epilogue: tanh + v-dot, reduce over n within block ---
        // D frag mapping: col = l&15, row = (l>>4)*4 + j  [m89-verified]
        #pragma unroll
        for (int mi = 0; mi < 4; ++mi) {
            float P[4] = {0.f, 0.f, 0.f, 0.f};
            #pragma unroll
            for (int ni = 0; ni < 4; ++ni) {
                const int nl = wn * 64 + ni * 16 + (l & 15);
                const float tvv = tv_s[nt2][nl];
                const float vvv = vv_s[nt2][nl];
                #pragma unroll
                for (int j = 0; j < 4; ++j) {
                    float e = fast_tanh(acc[mi][ni][j] + tvv);
                    P[j] = fmaf(e, vvv, P[j]);
                }
            }
            #pragma unroll
            for (int j = 0; j < 4; ++j) {
                float p = P[j];
                p += __shfl_xor(p, 1);
                p += __shfl_xor(p, 2);
                p += __shfl_xor(p, 4);
                p += __shfl_xor(p, 8);
                if ((l & 15) == 0)
                    red[wn][wm * 64 + mi * 16 + (l >> 4) * 4 + j] = p;
            }
        }
        __syncthreads();
        if (tid < BME)
            att_part[(size_t)(m0 + tid) * NTILES + (ypair * 2 + nt2)] =
                red[0][tid] + red[1][tid];
        // next nt2 iteration's first in-loop __syncthreads orders red reuse
    }
}

// ---------------------------------------------------------------------------
// Kernel C: reduce partials + masked softmax over s per batch. One block per b.
// ---------------------------------------------------------------------------
__global__ __launch_bounds__(256) void softmax_kernel(
        const float* __restrict__ att_part,  // (B*S, NTILES)
        const int* __restrict__ mask,        // (B, S)
        float* __restrict__ wout)            // (B, S)
{
    __shared__ float red[256];
    const int b = blockIdx.x;
    const int tid = threadIdx.x;

    float x0 = 0.f, x1 = 0.f;
    #pragma unroll
    for (int p = 0; p < NTILES; ++p) {
        x0 += att_part[(size_t)(b * S_ + tid) * NTILES + p];
        x1 += att_part[(size_t)(b * S_ + 256 + tid) * NTILES + p];
    }
    bool m0v = (mask[b * S_ + tid] != 0);
    bool m1v = (mask[b * S_ + 256 + tid] != 0);
    if (!m0v) x0 = -INFINITY;
    if (!m1v) x1 = -INFINITY;

    float m = fmaxf(x0, x1);
    red[tid] = m;
    __syncthreads();
    for (int o = 128; o > 0; o >>= 1) {
        if (tid < o) red[tid] = fmaxf(red[tid], red[tid + o]);
        __syncthreads();
    }
    m = red[0];
    __syncthreads();

    float e0 = m0v ? expf(x0 - m) : 0.f;
    float e1 = m1v ? expf(x1 - m) : 0.f;
    red[tid] = e0 + e1;
    __syncthreads();
    for (int o = 128; o > 0; o >>= 1) {
        if (tid < o) red[tid] += red[tid + o];
        __syncthreads();
    }
    const float inv = 1.f / red[0];
    wout[b * S_ + tid] = e0 * inv;
    wout[b * S_ + 256 + tid] = e1 * inv;
}

// ---------------------------------------------------------------------------
// Kernel D: out_part[sc][b][e] = sum_{s in chunk sc} wgt[b,s]*enc[b,s,e]
// float4 per lane, s split 4-ways for occupancy. Then a tiny 4-way reduce.
// ---------------------------------------------------------------------------
__global__ __launch_bounds__(256) void attout_part_kernel(
        const float* __restrict__ wgt,    // (B, S)
        const float* __restrict__ enc,    // (B, S, E2)
        float* __restrict__ out_part)     // (4, B, E2)
{
    __shared__ float wsm[128];
    const int b  = blockIdx.y;
    const int sc = blockIdx.x;            // 0..3
    const int tid = threadIdx.x;          // e4 index, covers E2 = 256*4
    if (tid < 128) wsm[tid] = wgt[b * S_ + sc * 128 + tid];
    __syncthreads();

    const float4* ep = reinterpret_cast<const float4*>(
        enc + (size_t)b * S_ * E2_ + (size_t)sc * 128 * E2_);
    float4 acc = {0.f, 0.f, 0.f, 0.f};
    #pragma unroll 8
    for (int s = 0; s < 128; ++s) {
        float4 e4 = ep[(size_t)s * (E2_ / 4) + tid];
        const float ws = wsm[s];
        acc.x = fmaf(ws, e4.x, acc.x);
        acc.y = fmaf(ws, e4.y, acc.y);
        acc.z = fmaf(ws, e4.z, acc.z);
        acc.w = fmaf(ws, e4.w, acc.w);
    }
    reinterpret_cast<float4*>(out_part + ((size_t)sc * B_ + b) * E2_)[tid] = acc;
}

__global__ __launch_bounds__(256) void attout_reduce_kernel(
        const float* __restrict__ out_part,  // (4, B, E2)
        float* __restrict__ out)             // (B, E2)
{
    const int idx = blockIdx.x * 256 + threadIdx.x;   // float4 index
    const int n4 = (B_ * E2_) / 4;
    const float4* p = reinterpret_cast<const float4*>(out_part);
    float4 a = p[idx];
    float4 bq = p[idx + n4];
    float4 c = p[idx + 2 * n4];
    float4 d = p[idx + 3 * n4];
    float4 r;
    r.x = (a.x + bq.x) + (c.x + d.x);
    r.y = (a.y + bq.y) + (c.y + d.y);
    r.z = (a.z + bq.z) + (c.z + d.z);
    r.w = (a.w + bq.w) + (c.w + d.w);
    reinterpret_cast<float4*>(out)[idx] = r;
}

// ---------------------------------------------------------------------------
extern "C" void kernel_launch(void* const* d_in, const int* in_sizes, int n_in,
                              void* d_out, int out_size, void* d_ws, size_t ws_size,
                              hipStream_t stream) {
    const float* dec  = (const float*)d_in[0];   // (B, D)
    const float* enc  = (const float*)d_in[1];   // (B, S, E2)
    const int*   mask = (const int*)d_in[2];     // (B, S)
    const float* w    = (const float*)d_in[3];   // (D, D+E2)
    const float* bias = (const float*)d_in[4];   // (D)
    const float* v    = (const float*)d_in[5];   // (D)
    float* out = (float*)d_out;                  // (B, 1, E2)

    // workspace layout
    float* t_buf    = (float*)d_ws;                      // B*D          f32
    float* att_part = t_buf + B_ * D_;                   // B*S*NTILES   f32
    float* wgt_buf  = att_part + B_ * S_ * NTILES;       // B*S          f32
    float* out_part = wgt_buf + B_ * S_;                 // 4*B*E2       f32
    unsigned short* encb = (unsigned short*)(out_part + 4 * B_ * E2_); // bf16
    unsigned short* web  = encb + (size_t)B_ * S_ * E2_;               // bf16

    const int enc_n8 = (B_ * S_ * E2_) / 8;
    conv_enc_kernel<<<4096, 256, 0, stream>>>(enc, encb, enc_n8);
    conv_we_kernel<<<D_, 256, 0, stream>>>(w, web);
    dec_proj_kernel<<<D_, 256, 0, stream>>>(dec, w, bias, t_buf);
    energy_mfma_kernel<<<dim3(256, 4), 256, 0, stream>>>(
        encb, web, t_buf, v, att_part);
    softmax_kernel<<<B_, 256, 0, stream>>>(att_part, mask, wgt_buf);
    attout_part_kernel<<<dim3(4, B_), 256, 0, stream>>>(wgt_buf, enc, out_part);
    attout_reduce_kernel<<<(B_ * E2_ / 4) / 256, 256, 0, stream>>>(out_part, out);
}